// Round 11
// baseline (194.215 us; speedup 1.0000x reference)
//
#include <hip/hip_runtime.h>
#include <hip/hip_bf16.h>

// Problem constants
#define B_DIM 1024
#define L_DIM 32
#define K_DIM 8
#define G_DIM 8
#define C_DIM 128
#define S_DIM 32
#define DIN   104   // 2L + K + S

typedef __bf16  bf16x8 __attribute__((ext_vector_type(8)));
typedef float   f32x4  __attribute__((ext_vector_type(4)));
typedef float   f32x2  __attribute__((ext_vector_type(2)));

union frag_u { uint4 u; bf16x8 v; };

static __device__ __forceinline__ unsigned int pk2(float a, float b) {
    __hip_bfloat162 h = __float22bfloat162_rn(make_float2(a, b));  // v_cvt_pk_bf16_f32
    union { __hip_bfloat162 h; unsigned int u; } v; v.h = h; return v.u;
}
static __device__ __forceinline__ unsigned int pk2v(f32x2 a) { return pk2(a.x, a.y); }
static __device__ __forceinline__ bf16x8 ld_frag(const unsigned short* p) {
    frag_u t; t.u = *(const uint4*)p; return t.v;
}

#define LOG2E 1.44269504f

// ---------------------------------------------------------------------------
// Kernel 1 (merged): blocks [0,1024): per-b decisions -> cvarpk byte +
//   parent-mask bits wsmask[l][b][g]; zero d_out[b].
//   blocks [1024,1536): W1/W2 fp32->bf16 fragment repack.
// (R2-R8 measured: total-fused gap constant ~92us across prep variants ->
//  prep is not the limiter; unchanged.)
// ---------------------------------------------------------------------------
__global__ __launch_bounds__(256) void prep_kernel(
    const float* __restrict__ u_gumbel,      // [B,L,K]
    const float* __restrict__ u_adj,         // [B,G,K,K]
    const float* __restrict__ target_params, // [L,K]
    const float* __restrict__ enco_theta,    // [K,K]
    const float* __restrict__ enco_gamma,    // [K,K]
    const int*   __restrict__ target,        // [B]
    const float* __restrict__ W1,            // [32][128][104]
    const float* __restrict__ W2,            // [32][128][128]
    float*       __restrict__ out,           // [B]
    unsigned char* __restrict__ cvarpk,      // [B][32]  cvar | tflag<<3
    unsigned int*  __restrict__ wsmask,      // [L][B][G]
    unsigned short* __restrict__ wscr)       // bf16 frag-ordered weights
{
    const int t = threadIdx.x;
    if (blockIdx.x >= 1024) {
        int gtid  = (blockIdx.x - 1024) * 256 + t;   // [0, 131072)
        int lane  = gtid & 63;
        int ks    = (gtid >> 6) & 3;
        int mt    = (gtid >> 8) & 3;
        int wm    = (gtid >> 10) & 1;
        int l     = (gtid >> 11) & 31;
        int which = gtid >> 16;
        int m  = 16 * (4 * wm + mt) + (lane & 15);
        int k0 = ks * 32 + (lane >> 4) * 8;
        uint4 o;
        if (which == 0) {
            if (k0 >= 104) {
                o = make_uint4(0u, 0u, 0u, 0u);
            } else {
                const float* p = W1 + (size_t)l * 13312 + m * 104 + k0;
                float4 a = *(const float4*)p, bq = *(const float4*)(p + 4);
                o = make_uint4(pk2(a.x, a.y), pk2(a.z, a.w), pk2(bq.x, bq.y), pk2(bq.z, bq.w));
            }
        } else {
            const float* p = W2 + (size_t)l * 16384 + m * 128 + k0;
            float4 a = *(const float4*)p, bq = *(const float4*)(p + 4);
            o = make_uint4(pk2(a.x, a.y), pk2(a.z, a.w), pk2(bq.x, bq.y), pk2(bq.z, bq.w));
        }
        *(uint4*)(wscr + (size_t)gtid * 8) = o;
        return;
    }

    __shared__ double ep[64];
    __shared__ unsigned char cv8[32];
    __shared__ unsigned long long adjb[8];
    const int b = blockIdx.x;
    if (t < 64) {
        double th = (double)enco_theta[t];
        double ga = (double)enco_gamma[t];
        ep[t] = (1.0 / (1.0 + exp(-th))) * (1.0 / (1.0 + exp(-ga)));
    }
    if (t == 0) out[b] = 0.0f;
    __syncthreads();

    {
        const int l = t >> 3, k = t & 7;
        float uf = u_gumbel[b * 256 + t];
        float gf = -__logf(-__logf(uf + 1e-10f) + 1e-10f);
        float vf = target_params[t] + gf;
        float vm = vf; int bk = k;
        #pragma unroll
        for (int off = 1; off < 8; off <<= 1) {
            float ov = __shfl_xor(vm, off, 64);
            int  obk = __shfl_xor(bk, off, 64);
            if (ov > vm || (ov == vm && obk < bk)) { vm = ov; bk = obk; }
        }
        int amb = ((k != bk) && (vm - vf < 1e-3f)) ? 1 : 0;
        #pragma unroll
        for (int off = 1; off < 8; off <<= 1) amb |= __shfl_xor(amb, off, 64);
        if (amb) {
            double ud = (double)uf;
            double gd = -log(-log(ud + 1e-10) + 1e-10);
            double vd = (double)target_params[t] + gd;
            int bk2 = k;
            #pragma unroll
            for (int off = 1; off < 8; off <<= 1) {
                double ov = __shfl_xor(vd, off, 64);
                int   obk = __shfl_xor(bk2, off, 64);
                if (ov > vd || (ov == vd && obk < bk2)) { vd = ov; bk2 = obk; }
            }
            bk = bk2;
        }
        if (k == 0) {
            int tg = target[b];
            unsigned char pkd = (unsigned char)(bk | ((bk == tg) ? 8 : 0));
            cvarpk[b * 32 + l] = pkd;
            cv8[l] = pkd;
        }
    }
    {
        const int wv = t >> 6, lane = t & 63;
        #pragma unroll
        for (int q = 0; q < 2; ++q) {
            int gg = wv + 4 * q;
            double u = (double)u_adj[b * 512 + gg * 64 + lane];
            unsigned long long m = __ballot(u < ep[lane]);
            if (lane == 0) adjb[gg] = m;
        }
    }
    __syncthreads();

    {
        const int g = t >> 5, l = t & 31;
        int lam = cv8[l] & 7;
        unsigned long long bits = adjb[g] >> lam;
        unsigned int mask = 0u;
        #pragma unroll
        for (int j = 0; j < 32; ++j) {
            int kap = cv8[j] & 7;
            mask |= ((unsigned int)(bits >> (kap * 8)) & 1u) << j;
        }
        mask &= ~(1u << l);
        wsmask[l * 8192 + b * 8 + g] = mask;
    }
}

// ---------------------------------------------------------------------------
// Kernel 2: wave-autonomous fused pipeline, X via LDS, packed-f32 epilogue.
// Grid 2048: blockIdx = grp*32 + l. 4 waves x 32 rows. No acc write-back:
// bias re-applied by pk_fma in consume passes. Stats/norm/dot on f32x2 to
// draw v_pk_{fma,add,mul}_f32 from the compiler (2 elem / 2 cyc issue).
// ---------------------------------------------------------------------------
__global__ __launch_bounds__(256, 4) void fused_kernel(
    const float* __restrict__ z_sample,   // [B,32]
    const float* __restrict__ z_mean,     // [B,32]
    const float* __restrict__ z_logstd,   // [B,32]
    const float* __restrict__ z_shared,   // [B,32]
    const float* __restrict__ pb1,        // [32][128]
    const float* __restrict__ g1w,
    const float* __restrict__ g1b,
    const float* __restrict__ pb2,
    const float* __restrict__ g2w,
    const float* __restrict__ g2b,
    const float* __restrict__ W3,         // [32][2][128]
    const float* __restrict__ pb3,        // [32][2]
    const float* __restrict__ tsc,        // [32][2]
    const unsigned short* __restrict__ wscr,    // bf16 frag-ordered weights
    const unsigned char*  __restrict__ cvarpk,  // [B][32]
    const unsigned int*   __restrict__ wsmask,  // [L][B][G]
    float* __restrict__ out)                    // [B]
{
    __shared__ __align__(16) unsigned short XH[4][32][136];  // wave-private X->H slices
    __shared__ float p_g1w[128], p_g1b[128], p_b1[128];
    __shared__ float p_g2w[128], p_g2b[128], p_b2[128];
    __shared__ float p_w3[2][128];
    __shared__ float p_b3[2], p_ts[2];
    __shared__ unsigned int  msk[128];
    __shared__ unsigned char cvl[16];

    const int tid  = threadIdx.x;
    const int w    = tid >> 6, lane = tid & 63;
    const int lo   = lane & 15, hi = lane >> 4;
    const int l    = blockIdx.x & 31;
    const int grp  = blockIdx.x >> 5;

    // ---- stage per-latent params + per-block decisions (ONLY barrier) ----
    if (tid < 128) {
        int c = tid;
        p_g1w[c] = g1w[l * 128 + c];  p_g1b[c] = g1b[l * 128 + c];
        p_b1[c]  = pb1[l * 128 + c];  p_w3[0][c] = W3[l * 256 + c];
        msk[c]   = wsmask[l * 8192 + grp * 128 + c];
    } else {
        int c = tid - 128;
        p_g2w[c] = g2w[l * 128 + c];  p_g2b[c] = g2b[l * 128 + c];
        p_b2[c]  = pb2[l * 128 + c];  p_w3[1][c] = W3[l * 256 + 128 + c];
    }
    if (tid < 16) cvl[tid] = cvarpk[(size_t)(grp * 16 + tid) * 32 + l];
    if (tid == 0) {
        p_b3[0] = pb3[l * 2];  p_b3[1] = pb3[l * 2 + 1];
        p_ts[0] = tsc[l * 2];  p_ts[1] = tsc[l * 2 + 1];
    }
    __syncthreads();  // B0 — the only barrier

    // ================= build X into wave-private LDS slice =================
    float zmv[2], zlv[2];
    #pragma unroll
    for (int nt = 0; nt < 2; ++nt) {
        int r  = nt * 16 + lo;
        int bl = (w * 32 + r) >> 3;
        int bg = grp * 16 + bl;
        zmv[nt] = z_mean[bg * 32 + l];      // early loads for the KLD tail
        zlv[nt] = z_logstd[bg * 32 + l];
        unsigned int m32 = msk[w * 32 + r];
        unsigned int mq  = (m32 >> (hi * 8)) & 0xffu;
        const float4* zp = (const float4*)(z_sample + bg * 32 + hi * 8);
        float4 za = zp[0], zb = zp[1];
        uint4 f0;   // masked z
        f0.x = pk2((mq & 1u)   ? za.x : 0.f, (mq & 2u)   ? za.y : 0.f);
        f0.y = pk2((mq & 4u)   ? za.z : 0.f, (mq & 8u)   ? za.w : 0.f);
        f0.z = pk2((mq & 16u)  ? zb.x : 0.f, (mq & 32u)  ? zb.y : 0.f);
        f0.w = pk2((mq & 64u)  ? zb.z : 0.f, (mq & 128u) ? zb.w : 0.f);
        uint4 f1;   // mask indicator bf16 1.0
        f1.x = ((mq & 1u)   ? 0x3F80u : 0u) | ((mq & 2u)   ? 0x3F800000u : 0u);
        f1.y = ((mq & 4u)   ? 0x3F80u : 0u) | ((mq & 8u)   ? 0x3F800000u : 0u);
        f1.z = ((mq & 16u)  ? 0x3F80u : 0u) | ((mq & 32u)  ? 0x3F800000u : 0u);
        f1.w = ((mq & 64u)  ? 0x3F80u : 0u) | ((mq & 128u) ? 0x3F800000u : 0u);
        unsigned int cb8 = cvl[bl];
        int lam = cb8 & 7, tf = (cb8 >> 3) & 1;
        int zsb = (hi == 0) ? 24 : (hi - 1) * 8;
        const float4* sp = (const float4*)(z_shared + bg * 32 + zsb);
        float4 sa = sp[0], sb = sp[1];
        uint4 fz;
        fz.x = pk2(sa.x, sa.y); fz.y = pk2(sa.z, sa.w);
        fz.z = pk2(sb.x, sb.y); fz.w = pk2(sb.z, sb.w);
        unsigned int ohw = tf ? (0x3F80u << ((lam & 1) << 4)) : 0u;
        int lq = lam >> 1;
        uint4 fo;
        fo.x = (lq == 0) ? ohw : 0u;
        fo.y = (lq == 1) ? ohw : 0u;
        fo.z = (lq == 2) ? ohw : 0u;
        fo.w = (lq == 3) ? ohw : 0u;
        bool h0 = (hi == 0);
        uint4 f2, f3;
        f2.x = h0 ? fo.x : fz.x;  f2.y = h0 ? fo.y : fz.y;
        f2.z = h0 ? fo.z : fz.z;  f2.w = h0 ? fo.w : fz.w;
        f3.x = h0 ? fz.x : 0u;    f3.y = h0 ? fz.y : 0u;
        f3.z = h0 ? fz.z : 0u;    f3.w = h0 ? fz.w : 0u;
        *(uint4*)&XH[w][r][hi * 8]      = f0;
        *(uint4*)&XH[w][r][32 + hi * 8] = f1;
        *(uint4*)&XH[w][r][64 + hi * 8] = f2;
        *(uint4*)&XH[w][r][96 + hi * 8] = f3;
    }
    // (in-wave LDS RAW ordered by lgkmcnt — no barrier)

    const float inv128 = 1.0f / 128.0f;
    const unsigned short* w1p = wscr + (size_t)(l * 32) * 512 + lane * 8;
    const unsigned short* w2p = wscr + (size_t)((32 + l) * 32) * 512 + lane * 8;

    // ================= GEMM1: 2-frag lookahead weight stream =================
    f32x4 acc[8][2];
    #pragma unroll
    for (int cb = 0; cb < 8; ++cb)
        #pragma unroll
        for (int nt = 0; nt < 2; ++nt) acc[cb][nt] = (f32x4){0.f, 0.f, 0.f, 0.f};
    {
        bf16x8 wfA[2], wfB[2];
        wfA[0] = ld_frag(w1p + 0 * 512);
        wfA[1] = ld_frag(w1p + 4 * 512);
        #pragma unroll
        for (int ks = 0; ks < 4; ++ks) {
            bf16x8 bf0 = ld_frag(&XH[w][lo][ks * 32 + hi * 8]);
            bf16x8 bf1 = ld_frag(&XH[w][16 + lo][ks * 32 + hi * 8]);
            #pragma unroll
            for (int p = 0; p < 4; ++p) {
                int ncb = (p < 3) ? (2 * p + 2) : 0;
                int nks = (p < 3) ? ks : ks + 1;
                if (p < 3 || ks < 3) {
                    wfB[0] = ld_frag(w1p + (ncb * 4 + nks) * 512);
                    wfB[1] = ld_frag(w1p + ((ncb + 1) * 4 + nks) * 512);
                }
                int cb = 2 * p;
                acc[cb][0]     = __builtin_amdgcn_mfma_f32_16x16x32_bf16(wfA[0], bf0, acc[cb][0], 0, 0, 0);
                acc[cb][1]     = __builtin_amdgcn_mfma_f32_16x16x32_bf16(wfA[0], bf1, acc[cb][1], 0, 0, 0);
                acc[cb + 1][0] = __builtin_amdgcn_mfma_f32_16x16x32_bf16(wfA[1], bf0, acc[cb + 1][0], 0, 0, 0);
                acc[cb + 1][1] = __builtin_amdgcn_mfma_f32_16x16x32_bf16(wfA[1], bf1, acc[cb + 1][1], 0, 0, 0);
                wfA[0] = wfB[0];  wfA[1] = wfB[1];
            }
        }
    }

    // ---- GN1 stats, packed f32x2, no acc write-back ----
    f32x2 s1v[2] = {(f32x2){0.f, 0.f}, (f32x2){0.f, 0.f}};
    f32x2 s2v[2] = {(f32x2){0.f, 0.f}, (f32x2){0.f, 0.f}};
    #pragma unroll
    for (int cb = 0; cb < 8; ++cb) {
        f32x2 bLo = *(const f32x2*)&p_b1[cb * 16 + hi * 4];
        f32x2 bHi = *(const f32x2*)&p_b1[cb * 16 + hi * 4 + 2];
        #pragma unroll
        for (int nt = 0; nt < 2; ++nt) {
            f32x2 vLo = (f32x2){acc[cb][nt][0], acc[cb][nt][1]} + bLo;
            f32x2 vHi = (f32x2){acc[cb][nt][2], acc[cb][nt][3]} + bHi;
            s1v[nt] += vLo + vHi;
            s2v[nt] += vLo * vLo + vHi * vHi;
        }
    }
    float rstd[2], nrm_off[2];
    #pragma unroll
    for (int nt = 0; nt < 2; ++nt) {
        float s1 = s1v[nt].x + s1v[nt].y;
        float s2 = s2v[nt].x + s2v[nt].y;
        s1 += __shfl_xor(s1, 16, 64);  s1 += __shfl_xor(s1, 32, 64);
        s2 += __shfl_xor(s2, 16, 64);  s2 += __shfl_xor(s2, 32, 64);
        float m_  = s1 * inv128;
        float var = s2 * inv128 - m_ * m_;
        float r   = rsqrtf(var + 1e-5f);
        rstd[nt] = r;  nrm_off[nt] = -m_ * r;
    }
    // ---- normalize + SiLU -> overwrite X slice with H (packed fma parts) ----
    #pragma unroll
    for (int cb = 0; cb < 8; ++cb) {
        f32x2 bLo = *(const f32x2*)&p_b1[cb * 16 + hi * 4];
        f32x2 bHi = *(const f32x2*)&p_b1[cb * 16 + hi * 4 + 2];
        f32x2 gwLo = *(const f32x2*)&p_g1w[cb * 16 + hi * 4];
        f32x2 gwHi = *(const f32x2*)&p_g1w[cb * 16 + hi * 4 + 2];
        f32x2 gbLo = *(const f32x2*)&p_g1b[cb * 16 + hi * 4];
        f32x2 gbHi = *(const f32x2*)&p_g1b[cb * 16 + hi * 4 + 2];
        #pragma unroll
        for (int nt = 0; nt < 2; ++nt) {
            f32x2 rr  = (f32x2){rstd[nt], rstd[nt]};
            f32x2 oo  = (f32x2){nrm_off[nt], nrm_off[nt]};
            f32x2 vLo = (f32x2){acc[cb][nt][0], acc[cb][nt][1]} + bLo;
            f32x2 vHi = (f32x2){acc[cb][nt][2], acc[cb][nt][3]} + bHi;
            f32x2 xLo = (vLo * rr + oo) * gwLo + gbLo;
            f32x2 xHi = (vHi * rr + oo) * gwHi + gbHi;
            f32x2 aLo = xLo * (f32x2){-LOG2E, -LOG2E};
            f32x2 aHi = xHi * (f32x2){-LOG2E, -LOG2E};
            f32x2 eLo = (f32x2){__builtin_amdgcn_exp2f(aLo.x), __builtin_amdgcn_exp2f(aLo.y)};
            f32x2 eHi = (f32x2){__builtin_amdgcn_exp2f(aHi.x), __builtin_amdgcn_exp2f(aHi.y)};
            f32x2 dLo = eLo + (f32x2){1.f, 1.f};
            f32x2 dHi = eHi + (f32x2){1.f, 1.f};
            f32x2 yLo = xLo * (f32x2){__builtin_amdgcn_rcpf(dLo.x), __builtin_amdgcn_rcpf(dLo.y)};
            f32x2 yHi = xHi * (f32x2){__builtin_amdgcn_rcpf(dHi.x), __builtin_amdgcn_rcpf(dHi.y)};
            *(uint2*)&XH[w][nt * 16 + lo][cb * 16 + hi * 4] =
                make_uint2(pk2v(yLo), pk2v(yHi));
        }
    }

    // ================= GEMM2: 2-frag lookahead weight stream =================
    #pragma unroll
    for (int cb = 0; cb < 8; ++cb)
        #pragma unroll
        for (int nt = 0; nt < 2; ++nt) acc[cb][nt] = (f32x4){0.f, 0.f, 0.f, 0.f};
    {
        bf16x8 wfA[2], wfB[2];
        wfA[0] = ld_frag(w2p + 0 * 512);
        wfA[1] = ld_frag(w2p + 4 * 512);
        #pragma unroll
        for (int ks = 0; ks < 4; ++ks) {
            bf16x8 bf0 = ld_frag(&XH[w][lo][ks * 32 + hi * 8]);
            bf16x8 bf1 = ld_frag(&XH[w][16 + lo][ks * 32 + hi * 8]);
            #pragma unroll
            for (int p = 0; p < 4; ++p) {
                int ncb = (p < 3) ? (2 * p + 2) : 0;
                int nks = (p < 3) ? ks : ks + 1;
                if (p < 3 || ks < 3) {
                    wfB[0] = ld_frag(w2p + (ncb * 4 + nks) * 512);
                    wfB[1] = ld_frag(w2p + ((ncb + 1) * 4 + nks) * 512);
                }
                int cb = 2 * p;
                acc[cb][0]     = __builtin_amdgcn_mfma_f32_16x16x32_bf16(wfA[0], bf0, acc[cb][0], 0, 0, 0);
                acc[cb][1]     = __builtin_amdgcn_mfma_f32_16x16x32_bf16(wfA[0], bf1, acc[cb][1], 0, 0, 0);
                acc[cb + 1][0] = __builtin_amdgcn_mfma_f32_16x16x32_bf16(wfA[1], bf0, acc[cb + 1][0], 0, 0, 0);
                acc[cb + 1][1] = __builtin_amdgcn_mfma_f32_16x16x32_bf16(wfA[1], bf1, acc[cb + 1][1], 0, 0, 0);
                wfA[0] = wfB[0];  wfA[1] = wfB[1];
            }
        }
    }

    // ---- GN2 stats, packed, no write-back ----
    f32x2 t1v[2] = {(f32x2){0.f, 0.f}, (f32x2){0.f, 0.f}};
    f32x2 t2v[2] = {(f32x2){0.f, 0.f}, (f32x2){0.f, 0.f}};
    #pragma unroll
    for (int cb = 0; cb < 8; ++cb) {
        f32x2 bLo = *(const f32x2*)&p_b2[cb * 16 + hi * 4];
        f32x2 bHi = *(const f32x2*)&p_b2[cb * 16 + hi * 4 + 2];
        #pragma unroll
        for (int nt = 0; nt < 2; ++nt) {
            f32x2 vLo = (f32x2){acc[cb][nt][0], acc[cb][nt][1]} + bLo;
            f32x2 vHi = (f32x2){acc[cb][nt][2], acc[cb][nt][3]} + bHi;
            t1v[nt] += vLo + vHi;
            t2v[nt] += vLo * vLo + vHi * vHi;
        }
    }
    float rstd2[2], off2[2];
    #pragma unroll
    for (int nt = 0; nt < 2; ++nt) {
        float s1 = t1v[nt].x + t1v[nt].y;
        float s2 = t2v[nt].x + t2v[nt].y;
        s1 += __shfl_xor(s1, 16, 64);  s1 += __shfl_xor(s1, 32, 64);
        s2 += __shfl_xor(s2, 16, 64);  s2 += __shfl_xor(s2, 32, 64);
        float m_  = s1 * inv128;
        float var = s2 * inv128 - m_ * m_;
        float r   = rsqrtf(var + 1e-5f);
        rstd2[nt] = r;  off2[nt] = -m_ * r;
    }
    // ---- normalize + SiLU + 128->2 dot, packed ----
    f32x2 pm2[2] = {(f32x2){0.f, 0.f}, (f32x2){0.f, 0.f}};
    f32x2 pl2[2] = {(f32x2){0.f, 0.f}, (f32x2){0.f, 0.f}};
    #pragma unroll
    for (int cb = 0; cb < 8; ++cb) {
        f32x2 bLo = *(const f32x2*)&p_b2[cb * 16 + hi * 4];
        f32x2 bHi = *(const f32x2*)&p_b2[cb * 16 + hi * 4 + 2];
        f32x2 gwLo = *(const f32x2*)&p_g2w[cb * 16 + hi * 4];
        f32x2 gwHi = *(const f32x2*)&p_g2w[cb * 16 + hi * 4 + 2];
        f32x2 gbLo = *(const f32x2*)&p_g2b[cb * 16 + hi * 4];
        f32x2 gbHi = *(const f32x2*)&p_g2b[cb * 16 + hi * 4 + 2];
        f32x2 w0Lo = *(const f32x2*)&p_w3[0][cb * 16 + hi * 4];
        f32x2 w0Hi = *(const f32x2*)&p_w3[0][cb * 16 + hi * 4 + 2];
        f32x2 w1Lo = *(const f32x2*)&p_w3[1][cb * 16 + hi * 4];
        f32x2 w1Hi = *(const f32x2*)&p_w3[1][cb * 16 + hi * 4 + 2];
        #pragma unroll
        for (int nt = 0; nt < 2; ++nt) {
            f32x2 rr  = (f32x2){rstd2[nt], rstd2[nt]};
            f32x2 oo  = (f32x2){off2[nt], off2[nt]};
            f32x2 vLo = (f32x2){acc[cb][nt][0], acc[cb][nt][1]} + bLo;
            f32x2 vHi = (f32x2){acc[cb][nt][2], acc[cb][nt][3]} + bHi;
            f32x2 xLo = (vLo * rr + oo) * gwLo + gbLo;
            f32x2 xHi = (vHi * rr + oo) * gwHi + gbHi;
            f32x2 aLo = xLo * (f32x2){-LOG2E, -LOG2E};
            f32x2 aHi = xHi * (f32x2){-LOG2E, -LOG2E};
            f32x2 eLo = (f32x2){__builtin_amdgcn_exp2f(aLo.x), __builtin_amdgcn_exp2f(aLo.y)};
            f32x2 eHi = (f32x2){__builtin_amdgcn_exp2f(aHi.x), __builtin_amdgcn_exp2f(aHi.y)};
            f32x2 dLo = eLo + (f32x2){1.f, 1.f};
            f32x2 dHi = eHi + (f32x2){1.f, 1.f};
            f32x2 yLo = xLo * (f32x2){__builtin_amdgcn_rcpf(dLo.x), __builtin_amdgcn_rcpf(dLo.y)};
            f32x2 yHi = xHi * (f32x2){__builtin_amdgcn_rcpf(dHi.x), __builtin_amdgcn_rcpf(dHi.y)};
            pm2[nt] += yLo * w0Lo + yHi * w0Hi;
            pl2[nt] += yLo * w1Lo + yHi * w1Hi;
        }
    }

    // ---- tanh-scale + KLD + mean over g + accumulate ----
    {
        float sc0 = __expf(p_ts[0]), sc1 = __expf(p_ts[1]);
        float is0 = __expf(-p_ts[0]), is1 = __expf(-p_ts[1]);
        #pragma unroll
        for (int nt = 0; nt < 2; ++nt) {
            float pmp = pm2[nt].x + pm2[nt].y;
            float plp = pl2[nt].x + pl2[nt].y;
            pmp += __shfl_xor(pmp, 16, 64);  pmp += __shfl_xor(pmp, 32, 64);
            plp += __shfl_xor(plp, 16, 64);  plp += __shfl_xor(plp, 32, 64);
            float pm = pmp + p_b3[0];
            float pl = plp + p_b3[1];
            float e0 = __expf(2.0f * pm * is0);
            pm = (1.0f - 2.0f * __fdividef(1.0f, e0 + 1.0f)) * sc0;
            float e1 = __expf(2.0f * pl * is1);
            pl = (1.0f - 2.0f * __fdividef(1.0f, e1 + 1.0f)) * sc1;
            int r  = w * 32 + nt * 16 + lo;
            int bg = grp * 16 + (r >> 3);
            float vq = __expf(2.0f * zlv[nt]);
            float d  = zmv[nt] - pm;
            float kld = pl - zlv[nt] + (vq + d * d) * 0.5f * __expf(-2.0f * pl) - 0.5f;
            kld += __shfl_xor(kld, 1, 64);
            kld += __shfl_xor(kld, 2, 64);
            kld += __shfl_xor(kld, 4, 64);
            if (hi == 0 && (lo & 7) == 0) atomicAdd(&out[bg], kld * 0.125f);
        }
    }
}

extern "C" void kernel_launch(void* const* d_in, const int* in_sizes, int n_in,
                              void* d_out, int out_size, void* d_ws, size_t ws_size,
                              hipStream_t stream) {
    const float* z_sample      = (const float*)d_in[0];
    const int*   target        = (const int*)d_in[1];
    const float* z_mean        = (const float*)d_in[2];
    const float* z_logstd      = (const float*)d_in[3];
    const float* z_shared      = (const float*)d_in[4];
    const float* u_gumbel      = (const float*)d_in[5];
    const float* u_adj         = (const float*)d_in[6];
    const float* target_params = (const float*)d_in[7];
    const float* enco_theta    = (const float*)d_in[8];
    const float* enco_gamma    = (const float*)d_in[9];
    const float* W1            = (const float*)d_in[10];
    const float* pb1           = (const float*)d_in[11];
    const float* g1w           = (const float*)d_in[12];
    const float* g1b           = (const float*)d_in[13];
    const float* W2            = (const float*)d_in[14];
    const float* pb2           = (const float*)d_in[15];
    const float* g2w           = (const float*)d_in[16];
    const float* g2b           = (const float*)d_in[17];
    const float* W3            = (const float*)d_in[18];
    const float* pb3           = (const float*)d_in[19];
    const float* tsc           = (const float*)d_in[20];

    unsigned char* cvarpk = (unsigned char*)d_ws;                          // 32 KB
    unsigned int*  wsmask = (unsigned int*)((char*)d_ws + 32768);          // 1 MB
    unsigned short* wscr  = (unsigned short*)((char*)d_ws + 32768 + 1048576); // 2 MB

    prep_kernel<<<1536, 256, 0, stream>>>(u_gumbel, u_adj, target_params,
                                          enco_theta, enco_gamma, target,
                                          W1, W2, (float*)d_out,
                                          cvarpk, wsmask, wscr);
    fused_kernel<<<2048, 256, 0, stream>>>(z_sample, z_mean, z_logstd, z_shared,
                                           pb1, g1w, g1b, pb2, g2w, g2b,
                                           W3, pb3, tsc, wscr, cvarpk, wsmask,
                                           (float*)d_out);
}

// Round 12
// 157.058 us; speedup vs baseline: 1.2366x; 1.2366x over previous
//
#include <hip/hip_runtime.h>
#include <hip/hip_bf16.h>

// Problem constants
#define B_DIM 1024
#define L_DIM 32
#define K_DIM 8
#define G_DIM 8
#define C_DIM 128
#define S_DIM 32
#define DIN   104   // 2L + K + S

typedef __bf16  bf16x8 __attribute__((ext_vector_type(8)));
typedef float   f32x4  __attribute__((ext_vector_type(4)));
typedef float   f32x2  __attribute__((ext_vector_type(2)));

union frag_u { uint4 u; bf16x8 v; };

static __device__ __forceinline__ unsigned int pk2(float a, float b) {
    __hip_bfloat162 h = __float22bfloat162_rn(make_float2(a, b));  // v_cvt_pk_bf16_f32
    union { __hip_bfloat162 h; unsigned int u; } v; v.h = h; return v.u;
}
static __device__ __forceinline__ unsigned int pk2v(f32x2 a) { return pk2(a.x, a.y); }
static __device__ __forceinline__ bf16x8 ld_frag(const unsigned short* p) {
    frag_u t; t.u = *(const uint4*)p; return t.v;
}

#define LOG2E 1.44269504f

// ---------------------------------------------------------------------------
// Kernel 1 (merged): blocks [0,1024): per-b decisions -> cvarpk byte +
//   parent-mask bits wsmask[l][b][g]; zero d_out[b].
//   blocks [1024,1536): W1/W2 fp32->bf16 fragment repack.
// (R2-R8 measured: total-fused gap constant ~92us across prep variants ->
//  prep is not the limiter; unchanged.)
// ---------------------------------------------------------------------------
__global__ __launch_bounds__(256) void prep_kernel(
    const float* __restrict__ u_gumbel,      // [B,L,K]
    const float* __restrict__ u_adj,         // [B,G,K,K]
    const float* __restrict__ target_params, // [L,K]
    const float* __restrict__ enco_theta,    // [K,K]
    const float* __restrict__ enco_gamma,    // [K,K]
    const int*   __restrict__ target,        // [B]
    const float* __restrict__ W1,            // [32][128][104]
    const float* __restrict__ W2,            // [32][128][128]
    float*       __restrict__ out,           // [B]
    unsigned char* __restrict__ cvarpk,      // [B][32]  cvar | tflag<<3
    unsigned int*  __restrict__ wsmask,      // [L][B][G]
    unsigned short* __restrict__ wscr)       // bf16 frag-ordered weights
{
    const int t = threadIdx.x;
    if (blockIdx.x >= 1024) {
        int gtid  = (blockIdx.x - 1024) * 256 + t;   // [0, 131072)
        int lane  = gtid & 63;
        int ks    = (gtid >> 6) & 3;
        int mt    = (gtid >> 8) & 3;
        int wm    = (gtid >> 10) & 1;
        int l     = (gtid >> 11) & 31;
        int which = gtid >> 16;
        int m  = 16 * (4 * wm + mt) + (lane & 15);
        int k0 = ks * 32 + (lane >> 4) * 8;
        uint4 o;
        if (which == 0) {
            if (k0 >= 104) {
                o = make_uint4(0u, 0u, 0u, 0u);
            } else {
                const float* p = W1 + (size_t)l * 13312 + m * 104 + k0;
                float4 a = *(const float4*)p, bq = *(const float4*)(p + 4);
                o = make_uint4(pk2(a.x, a.y), pk2(a.z, a.w), pk2(bq.x, bq.y), pk2(bq.z, bq.w));
            }
        } else {
            const float* p = W2 + (size_t)l * 16384 + m * 128 + k0;
            float4 a = *(const float4*)p, bq = *(const float4*)(p + 4);
            o = make_uint4(pk2(a.x, a.y), pk2(a.z, a.w), pk2(bq.x, bq.y), pk2(bq.z, bq.w));
        }
        *(uint4*)(wscr + (size_t)gtid * 8) = o;
        return;
    }

    __shared__ double ep[64];
    __shared__ unsigned char cv8[32];
    __shared__ unsigned long long adjb[8];
    const int b = blockIdx.x;
    if (t < 64) {
        double th = (double)enco_theta[t];
        double ga = (double)enco_gamma[t];
        ep[t] = (1.0 / (1.0 + exp(-th))) * (1.0 / (1.0 + exp(-ga)));
    }
    if (t == 0) out[b] = 0.0f;
    __syncthreads();

    {
        const int l = t >> 3, k = t & 7;
        float uf = u_gumbel[b * 256 + t];
        float gf = -__logf(-__logf(uf + 1e-10f) + 1e-10f);
        float vf = target_params[t] + gf;
        float vm = vf; int bk = k;
        #pragma unroll
        for (int off = 1; off < 8; off <<= 1) {
            float ov = __shfl_xor(vm, off, 64);
            int  obk = __shfl_xor(bk, off, 64);
            if (ov > vm || (ov == vm && obk < bk)) { vm = ov; bk = obk; }
        }
        int amb = ((k != bk) && (vm - vf < 1e-3f)) ? 1 : 0;
        #pragma unroll
        for (int off = 1; off < 8; off <<= 1) amb |= __shfl_xor(amb, off, 64);
        if (amb) {
            double ud = (double)uf;
            double gd = -log(-log(ud + 1e-10) + 1e-10);
            double vd = (double)target_params[t] + gd;
            int bk2 = k;
            #pragma unroll
            for (int off = 1; off < 8; off <<= 1) {
                double ov = __shfl_xor(vd, off, 64);
                int   obk = __shfl_xor(bk2, off, 64);
                if (ov > vd || (ov == vd && obk < bk2)) { vd = ov; bk2 = obk; }
            }
            bk = bk2;
        }
        if (k == 0) {
            int tg = target[b];
            unsigned char pkd = (unsigned char)(bk | ((bk == tg) ? 8 : 0));
            cvarpk[b * 32 + l] = pkd;
            cv8[l] = pkd;
        }
    }
    {
        const int wv = t >> 6, lane = t & 63;
        #pragma unroll
        for (int q = 0; q < 2; ++q) {
            int gg = wv + 4 * q;
            double u = (double)u_adj[b * 512 + gg * 64 + lane];
            unsigned long long m = __ballot(u < ep[lane]);
            if (lane == 0) adjb[gg] = m;
        }
    }
    __syncthreads();

    {
        const int g = t >> 5, l = t & 31;
        int lam = cv8[l] & 7;
        unsigned long long bits = adjb[g] >> lam;
        unsigned int mask = 0u;
        #pragma unroll
        for (int j = 0; j < 32; ++j) {
            int kap = cv8[j] & 7;
            mask |= ((unsigned int)(bits >> (kap * 8)) & 1u) << j;
        }
        mask &= ~(1u << l);
        wsmask[l * 8192 + b * 8 + g] = mask;
    }
}

// ---------------------------------------------------------------------------
// Kernel 2: wave-autonomous fused pipeline, X via LDS, packed-f32 epilogue.
// Grid 2048: blockIdx = grp*32 + l. 4 waves x 32 rows.
// R11 post-mortem: (256,4)'s 128-reg cap + pk-op pair-alignment pressure =>
// ~450 B/thread scratch spill (WRITE_SIZE 236 MB), memory-bound collapse.
// R12: SAME packed epilogue, launch_bounds relaxed to (256,3) (~170 regs) so
// the allocator never spills; 3 waves/SIMD.
// ---------------------------------------------------------------------------
__global__ __launch_bounds__(256, 3) void fused_kernel(
    const float* __restrict__ z_sample,   // [B,32]
    const float* __restrict__ z_mean,     // [B,32]
    const float* __restrict__ z_logstd,   // [B,32]
    const float* __restrict__ z_shared,   // [B,32]
    const float* __restrict__ pb1,        // [32][128]
    const float* __restrict__ g1w,
    const float* __restrict__ g1b,
    const float* __restrict__ pb2,
    const float* __restrict__ g2w,
    const float* __restrict__ g2b,
    const float* __restrict__ W3,         // [32][2][128]
    const float* __restrict__ pb3,        // [32][2]
    const float* __restrict__ tsc,        // [32][2]
    const unsigned short* __restrict__ wscr,    // bf16 frag-ordered weights
    const unsigned char*  __restrict__ cvarpk,  // [B][32]
    const unsigned int*   __restrict__ wsmask,  // [L][B][G]
    float* __restrict__ out)                    // [B]
{
    __shared__ __align__(16) unsigned short XH[4][32][136];  // wave-private X->H slices
    __shared__ float p_g1w[128], p_g1b[128], p_b1[128];
    __shared__ float p_g2w[128], p_g2b[128], p_b2[128];
    __shared__ float p_w3[2][128];
    __shared__ float p_b3[2], p_ts[2];
    __shared__ unsigned int  msk[128];
    __shared__ unsigned char cvl[16];

    const int tid  = threadIdx.x;
    const int w    = tid >> 6, lane = tid & 63;
    const int lo   = lane & 15, hi = lane >> 4;
    const int l    = blockIdx.x & 31;
    const int grp  = blockIdx.x >> 5;

    // ---- stage per-latent params + per-block decisions (ONLY barrier) ----
    if (tid < 128) {
        int c = tid;
        p_g1w[c] = g1w[l * 128 + c];  p_g1b[c] = g1b[l * 128 + c];
        p_b1[c]  = pb1[l * 128 + c];  p_w3[0][c] = W3[l * 256 + c];
        msk[c]   = wsmask[l * 8192 + grp * 128 + c];
    } else {
        int c = tid - 128;
        p_g2w[c] = g2w[l * 128 + c];  p_g2b[c] = g2b[l * 128 + c];
        p_b2[c]  = pb2[l * 128 + c];  p_w3[1][c] = W3[l * 256 + 128 + c];
    }
    if (tid < 16) cvl[tid] = cvarpk[(size_t)(grp * 16 + tid) * 32 + l];
    if (tid == 0) {
        p_b3[0] = pb3[l * 2];  p_b3[1] = pb3[l * 2 + 1];
        p_ts[0] = tsc[l * 2];  p_ts[1] = tsc[l * 2 + 1];
    }
    __syncthreads();  // B0 — the only barrier

    // ================= build X into wave-private LDS slice =================
    float zmv[2], zlv[2];
    #pragma unroll
    for (int nt = 0; nt < 2; ++nt) {
        int r  = nt * 16 + lo;
        int bl = (w * 32 + r) >> 3;
        int bg = grp * 16 + bl;
        zmv[nt] = z_mean[bg * 32 + l];      // early loads for the KLD tail
        zlv[nt] = z_logstd[bg * 32 + l];
        unsigned int m32 = msk[w * 32 + r];
        unsigned int mq  = (m32 >> (hi * 8)) & 0xffu;
        const float4* zp = (const float4*)(z_sample + bg * 32 + hi * 8);
        float4 za = zp[0], zb = zp[1];
        uint4 f0;   // masked z
        f0.x = pk2((mq & 1u)   ? za.x : 0.f, (mq & 2u)   ? za.y : 0.f);
        f0.y = pk2((mq & 4u)   ? za.z : 0.f, (mq & 8u)   ? za.w : 0.f);
        f0.z = pk2((mq & 16u)  ? zb.x : 0.f, (mq & 32u)  ? zb.y : 0.f);
        f0.w = pk2((mq & 64u)  ? zb.z : 0.f, (mq & 128u) ? zb.w : 0.f);
        uint4 f1;   // mask indicator bf16 1.0
        f1.x = ((mq & 1u)   ? 0x3F80u : 0u) | ((mq & 2u)   ? 0x3F800000u : 0u);
        f1.y = ((mq & 4u)   ? 0x3F80u : 0u) | ((mq & 8u)   ? 0x3F800000u : 0u);
        f1.z = ((mq & 16u)  ? 0x3F80u : 0u) | ((mq & 32u)  ? 0x3F800000u : 0u);
        f1.w = ((mq & 64u)  ? 0x3F80u : 0u) | ((mq & 128u) ? 0x3F800000u : 0u);
        unsigned int cb8 = cvl[bl];
        int lam = cb8 & 7, tf = (cb8 >> 3) & 1;
        int zsb = (hi == 0) ? 24 : (hi - 1) * 8;
        const float4* sp = (const float4*)(z_shared + bg * 32 + zsb);
        float4 sa = sp[0], sb = sp[1];
        uint4 fz;
        fz.x = pk2(sa.x, sa.y); fz.y = pk2(sa.z, sa.w);
        fz.z = pk2(sb.x, sb.y); fz.w = pk2(sb.z, sb.w);
        unsigned int ohw = tf ? (0x3F80u << ((lam & 1) << 4)) : 0u;
        int lq = lam >> 1;
        uint4 fo;
        fo.x = (lq == 0) ? ohw : 0u;
        fo.y = (lq == 1) ? ohw : 0u;
        fo.z = (lq == 2) ? ohw : 0u;
        fo.w = (lq == 3) ? ohw : 0u;
        bool h0 = (hi == 0);
        uint4 f2, f3;
        f2.x = h0 ? fo.x : fz.x;  f2.y = h0 ? fo.y : fz.y;
        f2.z = h0 ? fo.z : fz.z;  f2.w = h0 ? fo.w : fz.w;
        f3.x = h0 ? fz.x : 0u;    f3.y = h0 ? fz.y : 0u;
        f3.z = h0 ? fz.z : 0u;    f3.w = h0 ? fz.w : 0u;
        *(uint4*)&XH[w][r][hi * 8]      = f0;
        *(uint4*)&XH[w][r][32 + hi * 8] = f1;
        *(uint4*)&XH[w][r][64 + hi * 8] = f2;
        *(uint4*)&XH[w][r][96 + hi * 8] = f3;
    }
    // (in-wave LDS RAW ordered by lgkmcnt — no barrier)

    const float inv128 = 1.0f / 128.0f;
    const unsigned short* w1p = wscr + (size_t)(l * 32) * 512 + lane * 8;
    const unsigned short* w2p = wscr + (size_t)((32 + l) * 32) * 512 + lane * 8;

    // ================= GEMM1: 2-frag lookahead weight stream =================
    f32x4 acc[8][2];
    #pragma unroll
    for (int cb = 0; cb < 8; ++cb)
        #pragma unroll
        for (int nt = 0; nt < 2; ++nt) acc[cb][nt] = (f32x4){0.f, 0.f, 0.f, 0.f};
    {
        bf16x8 wfA[2], wfB[2];
        wfA[0] = ld_frag(w1p + 0 * 512);
        wfA[1] = ld_frag(w1p + 4 * 512);
        #pragma unroll
        for (int ks = 0; ks < 4; ++ks) {
            bf16x8 bf0 = ld_frag(&XH[w][lo][ks * 32 + hi * 8]);
            bf16x8 bf1 = ld_frag(&XH[w][16 + lo][ks * 32 + hi * 8]);
            #pragma unroll
            for (int p = 0; p < 4; ++p) {
                int ncb = (p < 3) ? (2 * p + 2) : 0;
                int nks = (p < 3) ? ks : ks + 1;
                if (p < 3 || ks < 3) {
                    wfB[0] = ld_frag(w1p + (ncb * 4 + nks) * 512);
                    wfB[1] = ld_frag(w1p + ((ncb + 1) * 4 + nks) * 512);
                }
                int cb = 2 * p;
                acc[cb][0]     = __builtin_amdgcn_mfma_f32_16x16x32_bf16(wfA[0], bf0, acc[cb][0], 0, 0, 0);
                acc[cb][1]     = __builtin_amdgcn_mfma_f32_16x16x32_bf16(wfA[0], bf1, acc[cb][1], 0, 0, 0);
                acc[cb + 1][0] = __builtin_amdgcn_mfma_f32_16x16x32_bf16(wfA[1], bf0, acc[cb + 1][0], 0, 0, 0);
                acc[cb + 1][1] = __builtin_amdgcn_mfma_f32_16x16x32_bf16(wfA[1], bf1, acc[cb + 1][1], 0, 0, 0);
                wfA[0] = wfB[0];  wfA[1] = wfB[1];
            }
        }
    }

    // ---- GN1 stats, packed f32x2, bias folded in with write-back ----
    f32x2 s1v[2] = {(f32x2){0.f, 0.f}, (f32x2){0.f, 0.f}};
    f32x2 s2v[2] = {(f32x2){0.f, 0.f}, (f32x2){0.f, 0.f}};
    #pragma unroll
    for (int cb = 0; cb < 8; ++cb) {
        f32x2 bLo = *(const f32x2*)&p_b1[cb * 16 + hi * 4];
        f32x2 bHi = *(const f32x2*)&p_b1[cb * 16 + hi * 4 + 2];
        #pragma unroll
        for (int nt = 0; nt < 2; ++nt) {
            f32x2 vLo = (f32x2){acc[cb][nt][0], acc[cb][nt][1]} + bLo;
            f32x2 vHi = (f32x2){acc[cb][nt][2], acc[cb][nt][3]} + bHi;
            acc[cb][nt][0] = vLo.x;  acc[cb][nt][1] = vLo.y;
            acc[cb][nt][2] = vHi.x;  acc[cb][nt][3] = vHi.y;
            s1v[nt] += vLo + vHi;
            s2v[nt] += vLo * vLo + vHi * vHi;
        }
    }
    float rstd[2], nrm_off[2];
    #pragma unroll
    for (int nt = 0; nt < 2; ++nt) {
        float s1 = s1v[nt].x + s1v[nt].y;
        float s2 = s2v[nt].x + s2v[nt].y;
        s1 += __shfl_xor(s1, 16, 64);  s1 += __shfl_xor(s1, 32, 64);
        s2 += __shfl_xor(s2, 16, 64);  s2 += __shfl_xor(s2, 32, 64);
        float m_  = s1 * inv128;
        float var = s2 * inv128 - m_ * m_;
        float r   = rsqrtf(var + 1e-5f);
        rstd[nt] = r;  nrm_off[nt] = -m_ * r;
    }
    // ---- normalize + SiLU -> overwrite X slice with H (packed) ----
    #pragma unroll
    for (int cb = 0; cb < 8; ++cb) {
        f32x2 gwLo = *(const f32x2*)&p_g1w[cb * 16 + hi * 4];
        f32x2 gwHi = *(const f32x2*)&p_g1w[cb * 16 + hi * 4 + 2];
        f32x2 gbLo = *(const f32x2*)&p_g1b[cb * 16 + hi * 4];
        f32x2 gbHi = *(const f32x2*)&p_g1b[cb * 16 + hi * 4 + 2];
        #pragma unroll
        for (int nt = 0; nt < 2; ++nt) {
            f32x2 rr  = (f32x2){rstd[nt], rstd[nt]};
            f32x2 oo  = (f32x2){nrm_off[nt], nrm_off[nt]};
            f32x2 vLo = (f32x2){acc[cb][nt][0], acc[cb][nt][1]};
            f32x2 vHi = (f32x2){acc[cb][nt][2], acc[cb][nt][3]};
            f32x2 xLo = (vLo * rr + oo) * gwLo + gbLo;
            f32x2 xHi = (vHi * rr + oo) * gwHi + gbHi;
            f32x2 aLo = xLo * (f32x2){-LOG2E, -LOG2E};
            f32x2 aHi = xHi * (f32x2){-LOG2E, -LOG2E};
            f32x2 eLo = (f32x2){__builtin_amdgcn_exp2f(aLo.x), __builtin_amdgcn_exp2f(aLo.y)};
            f32x2 eHi = (f32x2){__builtin_amdgcn_exp2f(aHi.x), __builtin_amdgcn_exp2f(aHi.y)};
            f32x2 dLo = eLo + (f32x2){1.f, 1.f};
            f32x2 dHi = eHi + (f32x2){1.f, 1.f};
            f32x2 yLo = xLo * (f32x2){__builtin_amdgcn_rcpf(dLo.x), __builtin_amdgcn_rcpf(dLo.y)};
            f32x2 yHi = xHi * (f32x2){__builtin_amdgcn_rcpf(dHi.x), __builtin_amdgcn_rcpf(dHi.y)};
            *(uint2*)&XH[w][nt * 16 + lo][cb * 16 + hi * 4] =
                make_uint2(pk2v(yLo), pk2v(yHi));
        }
    }

    // ================= GEMM2: 2-frag lookahead weight stream =================
    #pragma unroll
    for (int cb = 0; cb < 8; ++cb)
        #pragma unroll
        for (int nt = 0; nt < 2; ++nt) acc[cb][nt] = (f32x4){0.f, 0.f, 0.f, 0.f};
    {
        bf16x8 wfA[2], wfB[2];
        wfA[0] = ld_frag(w2p + 0 * 512);
        wfA[1] = ld_frag(w2p + 4 * 512);
        #pragma unroll
        for (int ks = 0; ks < 4; ++ks) {
            bf16x8 bf0 = ld_frag(&XH[w][lo][ks * 32 + hi * 8]);
            bf16x8 bf1 = ld_frag(&XH[w][16 + lo][ks * 32 + hi * 8]);
            #pragma unroll
            for (int p = 0; p < 4; ++p) {
                int ncb = (p < 3) ? (2 * p + 2) : 0;
                int nks = (p < 3) ? ks : ks + 1;
                if (p < 3 || ks < 3) {
                    wfB[0] = ld_frag(w2p + (ncb * 4 + nks) * 512);
                    wfB[1] = ld_frag(w2p + ((ncb + 1) * 4 + nks) * 512);
                }
                int cb = 2 * p;
                acc[cb][0]     = __builtin_amdgcn_mfma_f32_16x16x32_bf16(wfA[0], bf0, acc[cb][0], 0, 0, 0);
                acc[cb][1]     = __builtin_amdgcn_mfma_f32_16x16x32_bf16(wfA[0], bf1, acc[cb][1], 0, 0, 0);
                acc[cb + 1][0] = __builtin_amdgcn_mfma_f32_16x16x32_bf16(wfA[1], bf0, acc[cb + 1][0], 0, 0, 0);
                acc[cb + 1][1] = __builtin_amdgcn_mfma_f32_16x16x32_bf16(wfA[1], bf1, acc[cb + 1][1], 0, 0, 0);
                wfA[0] = wfB[0];  wfA[1] = wfB[1];
            }
        }
    }

    // ---- GN2 stats, packed, bias write-back ----
    f32x2 t1v[2] = {(f32x2){0.f, 0.f}, (f32x2){0.f, 0.f}};
    f32x2 t2v[2] = {(f32x2){0.f, 0.f}, (f32x2){0.f, 0.f}};
    #pragma unroll
    for (int cb = 0; cb < 8; ++cb) {
        f32x2 bLo = *(const f32x2*)&p_b2[cb * 16 + hi * 4];
        f32x2 bHi = *(const f32x2*)&p_b2[cb * 16 + hi * 4 + 2];
        #pragma unroll
        for (int nt = 0; nt < 2; ++nt) {
            f32x2 vLo = (f32x2){acc[cb][nt][0], acc[cb][nt][1]} + bLo;
            f32x2 vHi = (f32x2){acc[cb][nt][2], acc[cb][nt][3]} + bHi;
            acc[cb][nt][0] = vLo.x;  acc[cb][nt][1] = vLo.y;
            acc[cb][nt][2] = vHi.x;  acc[cb][nt][3] = vHi.y;
            t1v[nt] += vLo + vHi;
            t2v[nt] += vLo * vLo + vHi * vHi;
        }
    }
    float rstd2[2], off2[2];
    #pragma unroll
    for (int nt = 0; nt < 2; ++nt) {
        float s1 = t1v[nt].x + t1v[nt].y;
        float s2 = t2v[nt].x + t2v[nt].y;
        s1 += __shfl_xor(s1, 16, 64);  s1 += __shfl_xor(s1, 32, 64);
        s2 += __shfl_xor(s2, 16, 64);  s2 += __shfl_xor(s2, 32, 64);
        float m_  = s1 * inv128;
        float var = s2 * inv128 - m_ * m_;
        float r   = rsqrtf(var + 1e-5f);
        rstd2[nt] = r;  off2[nt] = -m_ * r;
    }
    // ---- normalize + SiLU + 128->2 dot, packed ----
    f32x2 pm2[2] = {(f32x2){0.f, 0.f}, (f32x2){0.f, 0.f}};
    f32x2 pl2[2] = {(f32x2){0.f, 0.f}, (f32x2){0.f, 0.f}};
    #pragma unroll
    for (int cb = 0; cb < 8; ++cb) {
        f32x2 gwLo = *(const f32x2*)&p_g2w[cb * 16 + hi * 4];
        f32x2 gwHi = *(const f32x2*)&p_g2w[cb * 16 + hi * 4 + 2];
        f32x2 gbLo = *(const f32x2*)&p_g2b[cb * 16 + hi * 4];
        f32x2 gbHi = *(const f32x2*)&p_g2b[cb * 16 + hi * 4 + 2];
        f32x2 w0Lo = *(const f32x2*)&p_w3[0][cb * 16 + hi * 4];
        f32x2 w0Hi = *(const f32x2*)&p_w3[0][cb * 16 + hi * 4 + 2];
        f32x2 w1Lo = *(const f32x2*)&p_w3[1][cb * 16 + hi * 4];
        f32x2 w1Hi = *(const f32x2*)&p_w3[1][cb * 16 + hi * 4 + 2];
        #pragma unroll
        for (int nt = 0; nt < 2; ++nt) {
            f32x2 rr  = (f32x2){rstd2[nt], rstd2[nt]};
            f32x2 oo  = (f32x2){off2[nt], off2[nt]};
            f32x2 vLo = (f32x2){acc[cb][nt][0], acc[cb][nt][1]};
            f32x2 vHi = (f32x2){acc[cb][nt][2], acc[cb][nt][3]};
            f32x2 xLo = (vLo * rr + oo) * gwLo + gbLo;
            f32x2 xHi = (vHi * rr + oo) * gwHi + gbHi;
            f32x2 aLo = xLo * (f32x2){-LOG2E, -LOG2E};
            f32x2 aHi = xHi * (f32x2){-LOG2E, -LOG2E};
            f32x2 eLo = (f32x2){__builtin_amdgcn_exp2f(aLo.x), __builtin_amdgcn_exp2f(aLo.y)};
            f32x2 eHi = (f32x2){__builtin_amdgcn_exp2f(aHi.x), __builtin_amdgcn_exp2f(aHi.y)};
            f32x2 dLo = eLo + (f32x2){1.f, 1.f};
            f32x2 dHi = eHi + (f32x2){1.f, 1.f};
            f32x2 yLo = xLo * (f32x2){__builtin_amdgcn_rcpf(dLo.x), __builtin_amdgcn_rcpf(dLo.y)};
            f32x2 yHi = xHi * (f32x2){__builtin_amdgcn_rcpf(dHi.x), __builtin_amdgcn_rcpf(dHi.y)};
            pm2[nt] += yLo * w0Lo + yHi * w0Hi;
            pl2[nt] += yLo * w1Lo + yHi * w1Hi;
        }
    }

    // ---- tanh-scale + KLD + mean over g + accumulate ----
    {
        float sc0 = __expf(p_ts[0]), sc1 = __expf(p_ts[1]);
        float is0 = __expf(-p_ts[0]), is1 = __expf(-p_ts[1]);
        #pragma unroll
        for (int nt = 0; nt < 2; ++nt) {
            float pmp = pm2[nt].x + pm2[nt].y;
            float plp = pl2[nt].x + pl2[nt].y;
            pmp += __shfl_xor(pmp, 16, 64);  pmp += __shfl_xor(pmp, 32, 64);
            plp += __shfl_xor(plp, 16, 64);  plp += __shfl_xor(plp, 32, 64);
            float pm = pmp + p_b3[0];
            float pl = plp + p_b3[1];
            float e0 = __expf(2.0f * pm * is0);
            pm = (1.0f - 2.0f * __fdividef(1.0f, e0 + 1.0f)) * sc0;
            float e1 = __expf(2.0f * pl * is1);
            pl = (1.0f - 2.0f * __fdividef(1.0f, e1 + 1.0f)) * sc1;
            int r  = w * 32 + nt * 16 + lo;
            int bg = grp * 16 + (r >> 3);
            float vq = __expf(2.0f * zlv[nt]);
            float d  = zmv[nt] - pm;
            float kld = pl - zlv[nt] + (vq + d * d) * 0.5f * __expf(-2.0f * pl) - 0.5f;
            kld += __shfl_xor(kld, 1, 64);
            kld += __shfl_xor(kld, 2, 64);
            kld += __shfl_xor(kld, 4, 64);
            if (hi == 0 && (lo & 7) == 0) atomicAdd(&out[bg], kld * 0.125f);
        }
    }
}

extern "C" void kernel_launch(void* const* d_in, const int* in_sizes, int n_in,
                              void* d_out, int out_size, void* d_ws, size_t ws_size,
                              hipStream_t stream) {
    const float* z_sample      = (const float*)d_in[0];
    const int*   target        = (const int*)d_in[1];
    const float* z_mean        = (const float*)d_in[2];
    const float* z_logstd      = (const float*)d_in[3];
    const float* z_shared      = (const float*)d_in[4];
    const float* u_gumbel      = (const float*)d_in[5];
    const float* u_adj         = (const float*)d_in[6];
    const float* target_params = (const float*)d_in[7];
    const float* enco_theta    = (const float*)d_in[8];
    const float* enco_gamma    = (const float*)d_in[9];
    const float* W1            = (const float*)d_in[10];
    const float* pb1           = (const float*)d_in[11];
    const float* g1w           = (const float*)d_in[12];
    const float* g1b           = (const float*)d_in[13];
    const float* W2            = (const float*)d_in[14];
    const float* pb2           = (const float*)d_in[15];
    const float* g2w           = (const float*)d_in[16];
    const float* g2b           = (const float*)d_in[17];
    const float* W3            = (const float*)d_in[18];
    const float* pb3           = (const float*)d_in[19];
    const float* tsc           = (const float*)d_in[20];

    unsigned char* cvarpk = (unsigned char*)d_ws;                          // 32 KB
    unsigned int*  wsmask = (unsigned int*)((char*)d_ws + 32768);          // 1 MB
    unsigned short* wscr  = (unsigned short*)((char*)d_ws + 32768 + 1048576); // 2 MB

    prep_kernel<<<1536, 256, 0, stream>>>(u_gumbel, u_adj, target_params,
                                          enco_theta, enco_gamma, target,
                                          W1, W2, (float*)d_out,
                                          cvarpk, wsmask, wscr);
    fused_kernel<<<2048, 256, 0, stream>>>(z_sample, z_mean, z_logstd, z_shared,
                                           pb1, g1w, g1b, pb2, g2w, g2b,
                                           W3, pb3, tsc, wscr, cvarpk, wsmask,
                                           (float*)d_out);
}

// Round 13
// 156.950 us; speedup vs baseline: 1.2374x; 1.0007x over previous
//
#include <hip/hip_runtime.h>
#include <hip/hip_bf16.h>

// Problem constants
#define B_DIM 1024
#define L_DIM 32
#define K_DIM 8
#define G_DIM 8
#define C_DIM 128
#define S_DIM 32
#define DIN   104   // 2L + K + S

typedef __bf16  bf16x8 __attribute__((ext_vector_type(8)));
typedef float   f32x4  __attribute__((ext_vector_type(4)));
typedef float   f32x2  __attribute__((ext_vector_type(2)));

union frag_u { uint4 u; bf16x8 v; };

static __device__ __forceinline__ unsigned int pk2(float a, float b) {
    __hip_bfloat162 h = __float22bfloat162_rn(make_float2(a, b));  // v_cvt_pk_bf16_f32
    union { __hip_bfloat162 h; unsigned int u; } v; v.h = h; return v.u;
}
static __device__ __forceinline__ unsigned int pk2v(f32x2 a) { return pk2(a.x, a.y); }
static __device__ __forceinline__ bf16x8 ld_frag(const unsigned short* p) {
    frag_u t; t.u = *(const uint4*)p; return t.v;
}

#define LOG2E 1.44269504f

// ---------------------------------------------------------------------------
// Kernel 1 (merged): blocks [0,1024): per-b decisions -> cvarpk byte +
//   parent-mask bits wsmask[l][b][g]; zero d_out[b].
//   blocks [1024,1536): W1/W2 fp32->bf16 fragment repack.
// (R2-R8 measured: total-fused gap constant ~92us across prep variants ->
//  prep is not the limiter; unchanged.)
// ---------------------------------------------------------------------------
__global__ __launch_bounds__(256) void prep_kernel(
    const float* __restrict__ u_gumbel,      // [B,L,K]
    const float* __restrict__ u_adj,         // [B,G,K,K]
    const float* __restrict__ target_params, // [L,K]
    const float* __restrict__ enco_theta,    // [K,K]
    const float* __restrict__ enco_gamma,    // [K,K]
    const int*   __restrict__ target,        // [B]
    const float* __restrict__ W1,            // [32][128][104]
    const float* __restrict__ W2,            // [32][128][128]
    float*       __restrict__ out,           // [B]
    unsigned char* __restrict__ cvarpk,      // [B][32]  cvar | tflag<<3
    unsigned int*  __restrict__ wsmask,      // [L][B][G]
    unsigned short* __restrict__ wscr)       // bf16 frag-ordered weights
{
    const int t = threadIdx.x;
    if (blockIdx.x >= 1024) {
        int gtid  = (blockIdx.x - 1024) * 256 + t;   // [0, 131072)
        int lane  = gtid & 63;
        int ks    = (gtid >> 6) & 3;
        int mt    = (gtid >> 8) & 3;
        int wm    = (gtid >> 10) & 1;
        int l     = (gtid >> 11) & 31;
        int which = gtid >> 16;
        int m  = 16 * (4 * wm + mt) + (lane & 15);
        int k0 = ks * 32 + (lane >> 4) * 8;
        uint4 o;
        if (which == 0) {
            if (k0 >= 104) {
                o = make_uint4(0u, 0u, 0u, 0u);
            } else {
                const float* p = W1 + (size_t)l * 13312 + m * 104 + k0;
                float4 a = *(const float4*)p, bq = *(const float4*)(p + 4);
                o = make_uint4(pk2(a.x, a.y), pk2(a.z, a.w), pk2(bq.x, bq.y), pk2(bq.z, bq.w));
            }
        } else {
            const float* p = W2 + (size_t)l * 16384 + m * 128 + k0;
            float4 a = *(const float4*)p, bq = *(const float4*)(p + 4);
            o = make_uint4(pk2(a.x, a.y), pk2(a.z, a.w), pk2(bq.x, bq.y), pk2(bq.z, bq.w));
        }
        *(uint4*)(wscr + (size_t)gtid * 8) = o;
        return;
    }

    __shared__ double ep[64];
    __shared__ unsigned char cv8[32];
    __shared__ unsigned long long adjb[8];
    const int b = blockIdx.x;
    if (t < 64) {
        double th = (double)enco_theta[t];
        double ga = (double)enco_gamma[t];
        ep[t] = (1.0 / (1.0 + exp(-th))) * (1.0 / (1.0 + exp(-ga)));
    }
    if (t == 0) out[b] = 0.0f;
    __syncthreads();

    {
        const int l = t >> 3, k = t & 7;
        float uf = u_gumbel[b * 256 + t];
        float gf = -__logf(-__logf(uf + 1e-10f) + 1e-10f);
        float vf = target_params[t] + gf;
        float vm = vf; int bk = k;
        #pragma unroll
        for (int off = 1; off < 8; off <<= 1) {
            float ov = __shfl_xor(vm, off, 64);
            int  obk = __shfl_xor(bk, off, 64);
            if (ov > vm || (ov == vm && obk < bk)) { vm = ov; bk = obk; }
        }
        int amb = ((k != bk) && (vm - vf < 1e-3f)) ? 1 : 0;
        #pragma unroll
        for (int off = 1; off < 8; off <<= 1) amb |= __shfl_xor(amb, off, 64);
        if (amb) {
            double ud = (double)uf;
            double gd = -log(-log(ud + 1e-10) + 1e-10);
            double vd = (double)target_params[t] + gd;
            int bk2 = k;
            #pragma unroll
            for (int off = 1; off < 8; off <<= 1) {
                double ov = __shfl_xor(vd, off, 64);
                int   obk = __shfl_xor(bk2, off, 64);
                if (ov > vd || (ov == vd && obk < bk2)) { vd = ov; bk2 = obk; }
            }
            bk = bk2;
        }
        if (k == 0) {
            int tg = target[b];
            unsigned char pkd = (unsigned char)(bk | ((bk == tg) ? 8 : 0));
            cvarpk[b * 32 + l] = pkd;
            cv8[l] = pkd;
        }
    }
    {
        const int wv = t >> 6, lane = t & 63;
        #pragma unroll
        for (int q = 0; q < 2; ++q) {
            int gg = wv + 4 * q;
            double u = (double)u_adj[b * 512 + gg * 64 + lane];
            unsigned long long m = __ballot(u < ep[lane]);
            if (lane == 0) adjb[gg] = m;
        }
    }
    __syncthreads();

    {
        const int g = t >> 5, l = t & 31;
        int lam = cv8[l] & 7;
        unsigned long long bits = adjb[g] >> lam;
        unsigned int mask = 0u;
        #pragma unroll
        for (int j = 0; j < 32; ++j) {
            int kap = cv8[j] & 7;
            mask |= ((unsigned int)(bits >> (kap * 8)) & 1u) << j;
        }
        mask &= ~(1u << l);
        wsmask[l * 8192 + b * 8 + g] = mask;
    }
}

// ---------------------------------------------------------------------------
// Kernel 2: wave-autonomous fused pipeline, X via LDS, packed-f32 epilogue.
// Grid 2048: blockIdx = grp*32 + l. 4 waves x 32 rows.
// R12 post-mortem: packed epilogue halved VALU-busy time (47->23us) but the
// (256,3) cap left ~16 regs of pk-pair-alignment spill (WRITE 35MB).
// R13: launch_bounds (256,2) — 256-reg budget, zero spill; measured occupancy
// at (256,3) was already 2 blocks/CU, so nothing is lost.
// ---------------------------------------------------------------------------
__global__ __launch_bounds__(256, 2) void fused_kernel(
    const float* __restrict__ z_sample,   // [B,32]
    const float* __restrict__ z_mean,     // [B,32]
    const float* __restrict__ z_logstd,   // [B,32]
    const float* __restrict__ z_shared,   // [B,32]
    const float* __restrict__ pb1,        // [32][128]
    const float* __restrict__ g1w,
    const float* __restrict__ g1b,
    const float* __restrict__ pb2,
    const float* __restrict__ g2w,
    const float* __restrict__ g2b,
    const float* __restrict__ W3,         // [32][2][128]
    const float* __restrict__ pb3,        // [32][2]
    const float* __restrict__ tsc,        // [32][2]
    const unsigned short* __restrict__ wscr,    // bf16 frag-ordered weights
    const unsigned char*  __restrict__ cvarpk,  // [B][32]
    const unsigned int*   __restrict__ wsmask,  // [L][B][G]
    float* __restrict__ out)                    // [B]
{
    __shared__ __align__(16) unsigned short XH[4][32][136];  // wave-private X->H slices
    __shared__ float p_g1w[128], p_g1b[128], p_b1[128];
    __shared__ float p_g2w[128], p_g2b[128], p_b2[128];
    __shared__ float p_w3[2][128];
    __shared__ float p_b3[2], p_ts[2];
    __shared__ unsigned int  msk[128];
    __shared__ unsigned char cvl[16];

    const int tid  = threadIdx.x;
    const int w    = tid >> 6, lane = tid & 63;
    const int lo   = lane & 15, hi = lane >> 4;
    const int l    = blockIdx.x & 31;
    const int grp  = blockIdx.x >> 5;

    // ---- stage per-latent params + per-block decisions (ONLY barrier) ----
    if (tid < 128) {
        int c = tid;
        p_g1w[c] = g1w[l * 128 + c];  p_g1b[c] = g1b[l * 128 + c];
        p_b1[c]  = pb1[l * 128 + c];  p_w3[0][c] = W3[l * 256 + c];
        msk[c]   = wsmask[l * 8192 + grp * 128 + c];
    } else {
        int c = tid - 128;
        p_g2w[c] = g2w[l * 128 + c];  p_g2b[c] = g2b[l * 128 + c];
        p_b2[c]  = pb2[l * 128 + c];  p_w3[1][c] = W3[l * 256 + 128 + c];
    }
    if (tid < 16) cvl[tid] = cvarpk[(size_t)(grp * 16 + tid) * 32 + l];
    if (tid == 0) {
        p_b3[0] = pb3[l * 2];  p_b3[1] = pb3[l * 2 + 1];
        p_ts[0] = tsc[l * 2];  p_ts[1] = tsc[l * 2 + 1];
    }
    __syncthreads();  // B0 — the only barrier

    // ================= build X into wave-private LDS slice =================
    #pragma unroll
    for (int nt = 0; nt < 2; ++nt) {
        int r  = nt * 16 + lo;
        int bl = (w * 32 + r) >> 3;
        int bg = grp * 16 + bl;
        unsigned int m32 = msk[w * 32 + r];
        unsigned int mq  = (m32 >> (hi * 8)) & 0xffu;
        const float4* zp = (const float4*)(z_sample + bg * 32 + hi * 8);
        float4 za = zp[0], zb = zp[1];
        uint4 f0;   // masked z
        f0.x = pk2((mq & 1u)   ? za.x : 0.f, (mq & 2u)   ? za.y : 0.f);
        f0.y = pk2((mq & 4u)   ? za.z : 0.f, (mq & 8u)   ? za.w : 0.f);
        f0.z = pk2((mq & 16u)  ? zb.x : 0.f, (mq & 32u)  ? zb.y : 0.f);
        f0.w = pk2((mq & 64u)  ? zb.z : 0.f, (mq & 128u) ? zb.w : 0.f);
        uint4 f1;   // mask indicator bf16 1.0
        f1.x = ((mq & 1u)   ? 0x3F80u : 0u) | ((mq & 2u)   ? 0x3F800000u : 0u);
        f1.y = ((mq & 4u)   ? 0x3F80u : 0u) | ((mq & 8u)   ? 0x3F800000u : 0u);
        f1.z = ((mq & 16u)  ? 0x3F80u : 0u) | ((mq & 32u)  ? 0x3F800000u : 0u);
        f1.w = ((mq & 64u)  ? 0x3F80u : 0u) | ((mq & 128u) ? 0x3F800000u : 0u);
        unsigned int cb8 = cvl[bl];
        int lam = cb8 & 7, tf = (cb8 >> 3) & 1;
        int zsb = (hi == 0) ? 24 : (hi - 1) * 8;
        const float4* sp = (const float4*)(z_shared + bg * 32 + zsb);
        float4 sa = sp[0], sb = sp[1];
        uint4 fz;
        fz.x = pk2(sa.x, sa.y); fz.y = pk2(sa.z, sa.w);
        fz.z = pk2(sb.x, sb.y); fz.w = pk2(sb.z, sb.w);
        unsigned int ohw = tf ? (0x3F80u << ((lam & 1) << 4)) : 0u;
        int lq = lam >> 1;
        uint4 fo;
        fo.x = (lq == 0) ? ohw : 0u;
        fo.y = (lq == 1) ? ohw : 0u;
        fo.z = (lq == 2) ? ohw : 0u;
        fo.w = (lq == 3) ? ohw : 0u;
        bool h0 = (hi == 0);
        uint4 f2, f3;
        f2.x = h0 ? fo.x : fz.x;  f2.y = h0 ? fo.y : fz.y;
        f2.z = h0 ? fo.z : fz.z;  f2.w = h0 ? fo.w : fz.w;
        f3.x = h0 ? fz.x : 0u;    f3.y = h0 ? fz.y : 0u;
        f3.z = h0 ? fz.z : 0u;    f3.w = h0 ? fz.w : 0u;
        *(uint4*)&XH[w][r][hi * 8]      = f0;
        *(uint4*)&XH[w][r][32 + hi * 8] = f1;
        *(uint4*)&XH[w][r][64 + hi * 8] = f2;
        *(uint4*)&XH[w][r][96 + hi * 8] = f3;
    }
    // (in-wave LDS RAW ordered by lgkmcnt — no barrier)

    const float inv128 = 1.0f / 128.0f;
    const unsigned short* w1p = wscr + (size_t)(l * 32) * 512 + lane * 8;
    const unsigned short* w2p = wscr + (size_t)((32 + l) * 32) * 512 + lane * 8;

    // ================= GEMM1: 2-frag lookahead weight stream =================
    f32x4 acc[8][2];
    #pragma unroll
    for (int cb = 0; cb < 8; ++cb)
        #pragma unroll
        for (int nt = 0; nt < 2; ++nt) acc[cb][nt] = (f32x4){0.f, 0.f, 0.f, 0.f};
    {
        bf16x8 wfA[2], wfB[2];
        wfA[0] = ld_frag(w1p + 0 * 512);
        wfA[1] = ld_frag(w1p + 4 * 512);
        #pragma unroll
        for (int ks = 0; ks < 4; ++ks) {
            bf16x8 bf0 = ld_frag(&XH[w][lo][ks * 32 + hi * 8]);
            bf16x8 bf1 = ld_frag(&XH[w][16 + lo][ks * 32 + hi * 8]);
            #pragma unroll
            for (int p = 0; p < 4; ++p) {
                int ncb = (p < 3) ? (2 * p + 2) : 0;
                int nks = (p < 3) ? ks : ks + 1;
                if (p < 3 || ks < 3) {
                    wfB[0] = ld_frag(w1p + (ncb * 4 + nks) * 512);
                    wfB[1] = ld_frag(w1p + ((ncb + 1) * 4 + nks) * 512);
                }
                int cb = 2 * p;
                acc[cb][0]     = __builtin_amdgcn_mfma_f32_16x16x32_bf16(wfA[0], bf0, acc[cb][0], 0, 0, 0);
                acc[cb][1]     = __builtin_amdgcn_mfma_f32_16x16x32_bf16(wfA[0], bf1, acc[cb][1], 0, 0, 0);
                acc[cb + 1][0] = __builtin_amdgcn_mfma_f32_16x16x32_bf16(wfA[1], bf0, acc[cb + 1][0], 0, 0, 0);
                acc[cb + 1][1] = __builtin_amdgcn_mfma_f32_16x16x32_bf16(wfA[1], bf1, acc[cb + 1][1], 0, 0, 0);
                wfA[0] = wfB[0];  wfA[1] = wfB[1];
            }
        }
    }

    // ---- GN1 stats, packed f32x2, bias folded in with write-back ----
    f32x2 s1v[2] = {(f32x2){0.f, 0.f}, (f32x2){0.f, 0.f}};
    f32x2 s2v[2] = {(f32x2){0.f, 0.f}, (f32x2){0.f, 0.f}};
    #pragma unroll
    for (int cb = 0; cb < 8; ++cb) {
        f32x2 bLo = *(const f32x2*)&p_b1[cb * 16 + hi * 4];
        f32x2 bHi = *(const f32x2*)&p_b1[cb * 16 + hi * 4 + 2];
        #pragma unroll
        for (int nt = 0; nt < 2; ++nt) {
            f32x2 vLo = (f32x2){acc[cb][nt][0], acc[cb][nt][1]} + bLo;
            f32x2 vHi = (f32x2){acc[cb][nt][2], acc[cb][nt][3]} + bHi;
            acc[cb][nt][0] = vLo.x;  acc[cb][nt][1] = vLo.y;
            acc[cb][nt][2] = vHi.x;  acc[cb][nt][3] = vHi.y;
            s1v[nt] += vLo + vHi;
            s2v[nt] += vLo * vLo + vHi * vHi;
        }
    }
    float rstd[2], nrm_off[2];
    #pragma unroll
    for (int nt = 0; nt < 2; ++nt) {
        float s1 = s1v[nt].x + s1v[nt].y;
        float s2 = s2v[nt].x + s2v[nt].y;
        s1 += __shfl_xor(s1, 16, 64);  s1 += __shfl_xor(s1, 32, 64);
        s2 += __shfl_xor(s2, 16, 64);  s2 += __shfl_xor(s2, 32, 64);
        float m_  = s1 * inv128;
        float var = s2 * inv128 - m_ * m_;
        float r   = rsqrtf(var + 1e-5f);
        rstd[nt] = r;  nrm_off[nt] = -m_ * r;
    }
    // ---- normalize + SiLU -> overwrite X slice with H (packed) ----
    #pragma unroll
    for (int cb = 0; cb < 8; ++cb) {
        f32x2 gwLo = *(const f32x2*)&p_g1w[cb * 16 + hi * 4];
        f32x2 gwHi = *(const f32x2*)&p_g1w[cb * 16 + hi * 4 + 2];
        f32x2 gbLo = *(const f32x2*)&p_g1b[cb * 16 + hi * 4];
        f32x2 gbHi = *(const f32x2*)&p_g1b[cb * 16 + hi * 4 + 2];
        #pragma unroll
        for (int nt = 0; nt < 2; ++nt) {
            f32x2 rr  = (f32x2){rstd[nt], rstd[nt]};
            f32x2 oo  = (f32x2){nrm_off[nt], nrm_off[nt]};
            f32x2 vLo = (f32x2){acc[cb][nt][0], acc[cb][nt][1]};
            f32x2 vHi = (f32x2){acc[cb][nt][2], acc[cb][nt][3]};
            f32x2 xLo = (vLo * rr + oo) * gwLo + gbLo;
            f32x2 xHi = (vHi * rr + oo) * gwHi + gbHi;
            f32x2 aLo = xLo * (f32x2){-LOG2E, -LOG2E};
            f32x2 aHi = xHi * (f32x2){-LOG2E, -LOG2E};
            f32x2 eLo = (f32x2){__builtin_amdgcn_exp2f(aLo.x), __builtin_amdgcn_exp2f(aLo.y)};
            f32x2 eHi = (f32x2){__builtin_amdgcn_exp2f(aHi.x), __builtin_amdgcn_exp2f(aHi.y)};
            f32x2 dLo = eLo + (f32x2){1.f, 1.f};
            f32x2 dHi = eHi + (f32x2){1.f, 1.f};
            f32x2 yLo = xLo * (f32x2){__builtin_amdgcn_rcpf(dLo.x), __builtin_amdgcn_rcpf(dLo.y)};
            f32x2 yHi = xHi * (f32x2){__builtin_amdgcn_rcpf(dHi.x), __builtin_amdgcn_rcpf(dHi.y)};
            *(uint2*)&XH[w][nt * 16 + lo][cb * 16 + hi * 4] =
                make_uint2(pk2v(yLo), pk2v(yHi));
        }
    }

    // ================= GEMM2: 2-frag lookahead weight stream =================
    #pragma unroll
    for (int cb = 0; cb < 8; ++cb)
        #pragma unroll
        for (int nt = 0; nt < 2; ++nt) acc[cb][nt] = (f32x4){0.f, 0.f, 0.f, 0.f};
    {
        bf16x8 wfA[2], wfB[2];
        wfA[0] = ld_frag(w2p + 0 * 512);
        wfA[1] = ld_frag(w2p + 4 * 512);
        #pragma unroll
        for (int ks = 0; ks < 4; ++ks) {
            bf16x8 bf0 = ld_frag(&XH[w][lo][ks * 32 + hi * 8]);
            bf16x8 bf1 = ld_frag(&XH[w][16 + lo][ks * 32 + hi * 8]);
            #pragma unroll
            for (int p = 0; p < 4; ++p) {
                int ncb = (p < 3) ? (2 * p + 2) : 0;
                int nks = (p < 3) ? ks : ks + 1;
                if (p < 3 || ks < 3) {
                    wfB[0] = ld_frag(w2p + (ncb * 4 + nks) * 512);
                    wfB[1] = ld_frag(w2p + ((ncb + 1) * 4 + nks) * 512);
                }
                int cb = 2 * p;
                acc[cb][0]     = __builtin_amdgcn_mfma_f32_16x16x32_bf16(wfA[0], bf0, acc[cb][0], 0, 0, 0);
                acc[cb][1]     = __builtin_amdgcn_mfma_f32_16x16x32_bf16(wfA[0], bf1, acc[cb][1], 0, 0, 0);
                acc[cb + 1][0] = __builtin_amdgcn_mfma_f32_16x16x32_bf16(wfA[1], bf0, acc[cb + 1][0], 0, 0, 0);
                acc[cb + 1][1] = __builtin_amdgcn_mfma_f32_16x16x32_bf16(wfA[1], bf1, acc[cb + 1][1], 0, 0, 0);
                wfA[0] = wfB[0];  wfA[1] = wfB[1];
            }
        }
    }

    // ---- GN2 stats, packed, bias write-back ----
    f32x2 t1v[2] = {(f32x2){0.f, 0.f}, (f32x2){0.f, 0.f}};
    f32x2 t2v[2] = {(f32x2){0.f, 0.f}, (f32x2){0.f, 0.f}};
    #pragma unroll
    for (int cb = 0; cb < 8; ++cb) {
        f32x2 bLo = *(const f32x2*)&p_b2[cb * 16 + hi * 4];
        f32x2 bHi = *(const f32x2*)&p_b2[cb * 16 + hi * 4 + 2];
        #pragma unroll
        for (int nt = 0; nt < 2; ++nt) {
            f32x2 vLo = (f32x2){acc[cb][nt][0], acc[cb][nt][1]} + bLo;
            f32x2 vHi = (f32x2){acc[cb][nt][2], acc[cb][nt][3]} + bHi;
            acc[cb][nt][0] = vLo.x;  acc[cb][nt][1] = vLo.y;
            acc[cb][nt][2] = vHi.x;  acc[cb][nt][3] = vHi.y;
            t1v[nt] += vLo + vHi;
            t2v[nt] += vLo * vLo + vHi * vHi;
        }
    }
    float rstd2[2], off2[2];
    #pragma unroll
    for (int nt = 0; nt < 2; ++nt) {
        float s1 = t1v[nt].x + t1v[nt].y;
        float s2 = t2v[nt].x + t2v[nt].y;
        s1 += __shfl_xor(s1, 16, 64);  s1 += __shfl_xor(s1, 32, 64);
        s2 += __shfl_xor(s2, 16, 64);  s2 += __shfl_xor(s2, 32, 64);
        float m_  = s1 * inv128;
        float var = s2 * inv128 - m_ * m_;
        float r   = rsqrtf(var + 1e-5f);
        rstd2[nt] = r;  off2[nt] = -m_ * r;
    }
    // ---- normalize + SiLU + 128->2 dot, packed ----
    f32x2 pm2[2] = {(f32x2){0.f, 0.f}, (f32x2){0.f, 0.f}};
    f32x2 pl2[2] = {(f32x2){0.f, 0.f}, (f32x2){0.f, 0.f}};
    #pragma unroll
    for (int cb = 0; cb < 8; ++cb) {
        f32x2 gwLo = *(const f32x2*)&p_g2w[cb * 16 + hi * 4];
        f32x2 gwHi = *(const f32x2*)&p_g2w[cb * 16 + hi * 4 + 2];
        f32x2 gbLo = *(const f32x2*)&p_g2b[cb * 16 + hi * 4];
        f32x2 gbHi = *(const f32x2*)&p_g2b[cb * 16 + hi * 4 + 2];
        f32x2 w0Lo = *(const f32x2*)&p_w3[0][cb * 16 + hi * 4];
        f32x2 w0Hi = *(const f32x2*)&p_w3[0][cb * 16 + hi * 4 + 2];
        f32x2 w1Lo = *(const f32x2*)&p_w3[1][cb * 16 + hi * 4];
        f32x2 w1Hi = *(const f32x2*)&p_w3[1][cb * 16 + hi * 4 + 2];
        #pragma unroll
        for (int nt = 0; nt < 2; ++nt) {
            f32x2 rr  = (f32x2){rstd2[nt], rstd2[nt]};
            f32x2 oo  = (f32x2){off2[nt], off2[nt]};
            f32x2 vLo = (f32x2){acc[cb][nt][0], acc[cb][nt][1]};
            f32x2 vHi = (f32x2){acc[cb][nt][2], acc[cb][nt][3]};
            f32x2 xLo = (vLo * rr + oo) * gwLo + gbLo;
            f32x2 xHi = (vHi * rr + oo) * gwHi + gbHi;
            f32x2 aLo = xLo * (f32x2){-LOG2E, -LOG2E};
            f32x2 aHi = xHi * (f32x2){-LOG2E, -LOG2E};
            f32x2 eLo = (f32x2){__builtin_amdgcn_exp2f(aLo.x), __builtin_amdgcn_exp2f(aLo.y)};
            f32x2 eHi = (f32x2){__builtin_amdgcn_exp2f(aHi.x), __builtin_amdgcn_exp2f(aHi.y)};
            f32x2 dLo = eLo + (f32x2){1.f, 1.f};
            f32x2 dHi = eHi + (f32x2){1.f, 1.f};
            f32x2 yLo = xLo * (f32x2){__builtin_amdgcn_rcpf(dLo.x), __builtin_amdgcn_rcpf(dLo.y)};
            f32x2 yHi = xHi * (f32x2){__builtin_amdgcn_rcpf(dHi.x), __builtin_amdgcn_rcpf(dHi.y)};
            pm2[nt] += yLo * w0Lo + yHi * w0Hi;
            pl2[nt] += yLo * w1Lo + yHi * w1Hi;
        }
    }

    // ---- tanh-scale + KLD + mean over g + accumulate (z loads at tail) ----
    {
        float sc0 = __expf(p_ts[0]), sc1 = __expf(p_ts[1]);
        float is0 = __expf(-p_ts[0]), is1 = __expf(-p_ts[1]);
        #pragma unroll
        for (int nt = 0; nt < 2; ++nt) {
            int r  = w * 32 + nt * 16 + lo;
            int bg = grp * 16 + (r >> 3);
            float zm = z_mean[bg * 32 + l];
            float zl = z_logstd[bg * 32 + l];
            float pmp = pm2[nt].x + pm2[nt].y;
            float plp = pl2[nt].x + pl2[nt].y;
            pmp += __shfl_xor(pmp, 16, 64);  pmp += __shfl_xor(pmp, 32, 64);
            plp += __shfl_xor(plp, 16, 64);  plp += __shfl_xor(plp, 32, 64);
            float pm = pmp + p_b3[0];
            float pl = plp + p_b3[1];
            float e0 = __expf(2.0f * pm * is0);
            pm = (1.0f - 2.0f * __fdividef(1.0f, e0 + 1.0f)) * sc0;
            float e1 = __expf(2.0f * pl * is1);
            pl = (1.0f - 2.0f * __fdividef(1.0f, e1 + 1.0f)) * sc1;
            float vq = __expf(2.0f * zl);
            float d  = zm - pm;
            float kld = pl - zl + (vq + d * d) * 0.5f * __expf(-2.0f * pl) - 0.5f;
            kld += __shfl_xor(kld, 1, 64);
            kld += __shfl_xor(kld, 2, 64);
            kld += __shfl_xor(kld, 4, 64);
            if (hi == 0 && (lo & 7) == 0) atomicAdd(&out[bg], kld * 0.125f);
        }
    }
}

extern "C" void kernel_launch(void* const* d_in, const int* in_sizes, int n_in,
                              void* d_out, int out_size, void* d_ws, size_t ws_size,
                              hipStream_t stream) {
    const float* z_sample      = (const float*)d_in[0];
    const int*   target        = (const int*)d_in[1];
    const float* z_mean        = (const float*)d_in[2];
    const float* z_logstd      = (const float*)d_in[3];
    const float* z_shared      = (const float*)d_in[4];
    const float* u_gumbel      = (const float*)d_in[5];
    const float* u_adj         = (const float*)d_in[6];
    const float* target_params = (const float*)d_in[7];
    const float* enco_theta    = (const float*)d_in[8];
    const float* enco_gamma    = (const float*)d_in[9];
    const float* W1            = (const float*)d_in[10];
    const float* pb1           = (const float*)d_in[11];
    const float* g1w           = (const float*)d_in[12];
    const float* g1b           = (const float*)d_in[13];
    const float* W2            = (const float*)d_in[14];
    const float* pb2           = (const float*)d_in[15];
    const float* g2w           = (const float*)d_in[16];
    const float* g2b           = (const float*)d_in[17];
    const float* W3            = (const float*)d_in[18];
    const float* pb3           = (const float*)d_in[19];
    const float* tsc           = (const float*)d_in[20];

    unsigned char* cvarpk = (unsigned char*)d_ws;                          // 32 KB
    unsigned int*  wsmask = (unsigned int*)((char*)d_ws + 32768);          // 1 MB
    unsigned short* wscr  = (unsigned short*)((char*)d_ws + 32768 + 1048576); // 2 MB

    prep_kernel<<<1536, 256, 0, stream>>>(u_gumbel, u_adj, target_params,
                                          enco_theta, enco_gamma, target,
                                          W1, W2, (float*)d_out,
                                          cvarpk, wsmask, wscr);
    fused_kernel<<<2048, 256, 0, stream>>>(z_sample, z_mean, z_logstd, z_shared,
                                           pb1, g1w, g1b, pb2, g2w, g2b,
                                           W3, pb3, tsc, wscr, cvarpk, wsmask,
                                           (float*)d_out);
}